// Round 2
// baseline (1036.156 us; speedup 1.0000x reference)
//
#include <hip/hip_runtime.h>

#define NDIM 128

// ---------------- CSR build ----------------
// NOTE: harness delivers integer inputs as int32 (const int*), NOT int64.

__global__ void deg_count_kernel(const int* __restrict__ ei, int E,
                                 int* __restrict__ deg) {
    int e = blockIdx.x * blockDim.x + threadIdx.x;
    if (e >= E) return;
    int dst = ei[(size_t)E + e];
    atomicAdd(&deg[dst], 1);
}

// single-block exclusive scan over deg[0..n) -> row_ptr[0..n], cursor copy
__global__ void scan_kernel(const int* __restrict__ deg, int* __restrict__ row_ptr,
                            int* __restrict__ cursor, int n) {
    __shared__ int wsum[16];
    __shared__ int woff[16];
    __shared__ int block_total;
    __shared__ int carry_s;
    const int tid  = threadIdx.x;
    const int lane = tid & 63;
    const int wid  = tid >> 6;
    if (tid == 0) carry_s = 0;
    __syncthreads();
    for (int base = 0; base < n; base += 1024) {
        int i = base + tid;
        int v = (i < n) ? deg[i] : 0;
        int inc = v;
        #pragma unroll
        for (int d = 1; d < 64; d <<= 1) {
            int t = __shfl_up(inc, d, 64);
            if (lane >= d) inc += t;
        }
        if (lane == 63) wsum[wid] = inc;
        __syncthreads();
        if (tid == 0) {
            int run = 0;
            #pragma unroll
            for (int w = 0; w < 16; ++w) { int s = wsum[w]; woff[w] = run; run += s; }
            block_total = run;
        }
        __syncthreads();
        if (i < n) {
            int ex = carry_s + woff[wid] + (inc - v);
            row_ptr[i] = ex;
            cursor[i]  = ex;
        }
        __syncthreads();
        if (tid == 0) carry_s += block_total;
        __syncthreads();
    }
    if (tid == 0) row_ptr[n] = carry_s;
}

__global__ void fill_csr_kernel(const int* __restrict__ ei, int E,
                                int* __restrict__ cursor, int* __restrict__ col) {
    int e = blockIdx.x * blockDim.x + threadIdx.x;
    if (e >= E) return;
    int src = ei[e];
    int dst = ei[(size_t)E + e];
    int slot = atomicAdd(&cursor[dst], 1);
    col[slot] = src;
}

// wcomb[k][o]: k<128 -> wl[o][k], k>=128 -> wr[o][k-128]   (256 x 128)
__global__ void build_wcomb_kernel(const float* __restrict__ wl,
                                   const float* __restrict__ wr,
                                   float* __restrict__ wcomb) {
    int idx = blockIdx.x * blockDim.x + threadIdx.x;
    if (idx >= 256 * 128) return;
    int k = idx >> 7, o = idx & 127;
    wcomb[idx] = (k < 128) ? wl[o * 128 + k] : wr[o * 128 + (k - 128)];
}

// ---------------- mean aggregation (CSR gather) ----------------

__global__ __launch_bounds__(256) void aggregate_kernel(
    const float* __restrict__ feat, const int* __restrict__ row_ptr,
    const int* __restrict__ col, float* __restrict__ agg, int n) {
    int node = blockIdx.x * 2 + (threadIdx.x >> 7);
    if (node >= n) return;
    int t = threadIdx.x & 127;
    int beg = row_ptr[node], end = row_ptr[node + 1];
    float acc = 0.f;
    for (int j = beg; j < end; ++j) {
        int s = col[j];
        acc += feat[(size_t)s * NDIM + t];
    }
    float inv = (end > beg) ? 1.0f / (float)(end - beg) : 0.f;
    agg[(size_t)node * NDIM + t] = acc * inv;
}

// ---------------- fused GEMM: out = [A0|A1] @ Wc + bias (, relu) ----------------
// M x 256 @ 256 x 128. BM=64, BK=32, 256 threads, 4x8 acc per thread.

__global__ __launch_bounds__(256) void gemm_fused_kernel(
    const float* __restrict__ A0, const float* __restrict__ A1,
    const float* __restrict__ Wc, const float* __restrict__ bias,
    float* __restrict__ out, int M, int do_relu) {
    __shared__ __align__(16) float As[64][36];
    __shared__ __align__(16) float Bs[32][128];
    const int tid = threadIdx.x;
    const int ty  = tid >> 4;   // 0..15, row group (4 rows each)
    const int tx  = tid & 15;   // 0..15, col group (8 cols each)
    const int m0  = blockIdx.x * 64;

    float acc[4][8];
    #pragma unroll
    for (int r = 0; r < 4; ++r)
        #pragma unroll
        for (int c = 0; c < 8; ++c) acc[r][c] = 0.f;

    for (int k0 = 0; k0 < 256; k0 += 32) {
        const float* Asrc = (k0 < 128) ? A0 : A1;
        const int kbase   = (k0 < 128) ? k0 : (k0 - 128);
        #pragma unroll
        for (int p = 0; p < 2; ++p) {
            int r  = (tid >> 3) + p * 32;
            int kk = (tid & 7) * 4;
            int gm = m0 + r;
            float4 v = make_float4(0.f, 0.f, 0.f, 0.f);
            if (gm < M) v = *(const float4*)&Asrc[(size_t)gm * NDIM + kbase + kk];
            *(float4*)&As[r][kk] = v;
        }
        #pragma unroll
        for (int p = 0; p < 4; ++p) {
            int r = (tid >> 5) + p * 8;
            int c = (tid & 31) * 4;
            *(float4*)&Bs[r][c] = *(const float4*)&Wc[(size_t)(k0 + r) * NDIM + c];
        }
        __syncthreads();
        #pragma unroll
        for (int kk = 0; kk < 32; ++kk) {
            float a[4];
            #pragma unroll
            for (int r = 0; r < 4; ++r) a[r] = As[ty * 4 + r][kk];
            float4 b0 = *(float4*)&Bs[kk][tx * 8];
            float4 b1 = *(float4*)&Bs[kk][tx * 8 + 4];
            float b[8] = {b0.x, b0.y, b0.z, b0.w, b1.x, b1.y, b1.z, b1.w};
            #pragma unroll
            for (int r = 0; r < 4; ++r)
                #pragma unroll
                for (int c = 0; c < 8; ++c)
                    acc[r][c] = fmaf(a[r], b[c], acc[r][c]);
        }
        __syncthreads();
    }

    #pragma unroll
    for (int r = 0; r < 4; ++r) {
        int gm = m0 + ty * 4 + r;
        if (gm >= M) continue;
        #pragma unroll
        for (int c = 0; c < 8; ++c) {
            int o = tx * 8 + c;
            float v = acc[r][c] + bias[o];
            if (do_relu) v = fmaxf(v, 0.f);
            acc[r][c] = v;
        }
        float4 o0 = make_float4(acc[r][0], acc[r][1], acc[r][2], acc[r][3]);
        float4 o1 = make_float4(acc[r][4], acc[r][5], acc[r][6], acc[r][7]);
        *(float4*)&out[(size_t)gm * NDIM + tx * 8]     = o0;
        *(float4*)&out[(size_t)gm * NDIM + tx * 8 + 4] = o1;
    }
}

// ---------------- launch ----------------

extern "C" void kernel_launch(void* const* d_in, const int* in_sizes, int n_in,
                              void* d_out, int out_size, void* d_ws, size_t ws_size,
                              hipStream_t stream) {
    const float* x    = (const float*)d_in[0];
    const int*   ei   = (const int*)d_in[1];   // int32! harness converts integer inputs
    const float* w1_l = (const float*)d_in[2];
    const float* b1   = (const float*)d_in[3];
    const float* w1_r = (const float*)d_in[4];
    const float* w2_l = (const float*)d_in[5];
    const float* b2   = (const float*)d_in[6];
    const float* w2_r = (const float*)d_in[7];
    const int N = in_sizes[0] / NDIM;
    const int E = in_sizes[1] / 2;
    float* out = (float*)d_out;

    char* ws = (char*)d_ws;
    size_t off = 0;
    auto take = [&](size_t bytes) -> char* {
        char* p = ws + off;
        off += (bytes + 255) & ~(size_t)255;
        return p;
    };
    int*   deg     = (int*)take((size_t)N * 4);
    int*   row_ptr = (int*)take((size_t)(N + 1) * 4);
    int*   cursor  = (int*)take((size_t)N * 4);
    int*   col     = (int*)take((size_t)E * 4);
    float* wc1     = (float*)take(256 * 128 * 4);
    float* wc2     = (float*)take(256 * 128 * 4);
    float* agg     = (float*)take((size_t)N * NDIM * 4);
    // h lives in d_out (layer-2 GEMM reads only its own block's rows -> in-place safe)

    hipMemsetAsync(deg, 0, (size_t)N * 4, stream);
    deg_count_kernel<<<(E + 255) / 256, 256, 0, stream>>>(ei, E, deg);
    scan_kernel<<<1, 1024, 0, stream>>>(deg, row_ptr, cursor, N);
    fill_csr_kernel<<<(E + 255) / 256, 256, 0, stream>>>(ei, E, cursor, col);
    build_wcomb_kernel<<<128, 256, 0, stream>>>(w1_l, w1_r, wc1);
    build_wcomb_kernel<<<128, 256, 0, stream>>>(w2_l, w2_r, wc2);

    // layer 1: h = relu([mean_agg(x) | x] @ Wc1 + b1)  -> d_out
    aggregate_kernel<<<(N + 1) / 2, 256, 0, stream>>>(x, row_ptr, col, agg, N);
    gemm_fused_kernel<<<(N + 63) / 64, 256, 0, stream>>>(agg, x, wc1, b1, out, N, 1);

    // layer 2: out = [mean_agg(h) | h] @ Wc2 + b2      -> d_out (in place)
    aggregate_kernel<<<(N + 1) / 2, 256, 0, stream>>>(out, row_ptr, col, agg, N);
    gemm_fused_kernel<<<(N + 63) / 64, 256, 0, stream>>>(agg, out, wc2, b2, out, N, 0);
}

// Round 3
// 548.080 us; speedup vs baseline: 1.8905x; 1.8905x over previous
//
#include <hip/hip_runtime.h>

#define NDIM 128
#define SCAN_CHUNK 1024

typedef unsigned short u16;
typedef unsigned int u32;

__device__ inline u16 f2bf(float f) {
    u32 u = __float_as_uint(f);
    u += 0x7fffu + ((u >> 16) & 1u);   // RNE
    return (u16)(u >> 16);
}

// ---------------- CSR build ----------------
// Harness delivers integer inputs as int32 (const int*).

__global__ void deg_count_kernel(const int* __restrict__ ei, int E,
                                 int* __restrict__ deg) {
    int e = blockIdx.x * blockDim.x + threadIdx.x;
    if (e >= E) return;
    atomicAdd(&deg[ei[(size_t)E + e]], 1);
}

// two-level scan: partial sums -> scan of partials -> final
__global__ __launch_bounds__(256) void scan_partial_kernel(
    const int* __restrict__ deg, int n, int* __restrict__ bsum) {
    int base = blockIdx.x * SCAN_CHUNK;
    int tid = threadIdx.x;
    int i = base + tid * 4;
    int4 v = make_int4(0, 0, 0, 0);
    if (i + 3 < n) v = *(const int4*)&deg[i];
    else {
        if (i + 0 < n) v.x = deg[i + 0];
        if (i + 1 < n) v.y = deg[i + 1];
        if (i + 2 < n) v.z = deg[i + 2];
        if (i + 3 < n) v.w = deg[i + 3];
    }
    int s = v.x + v.y + v.z + v.w;
    #pragma unroll
    for (int d = 1; d < 64; d <<= 1) s += __shfl_xor(s, d, 64);
    __shared__ int ws[4];
    if ((tid & 63) == 0) ws[tid >> 6] = s;
    __syncthreads();
    if (tid == 0) bsum[blockIdx.x] = ws[0] + ws[1] + ws[2] + ws[3];
}

__global__ void scan_bsums_kernel(int* __restrict__ bsum, int nb,
                                  int* __restrict__ total) {
    __shared__ int buf[512];
    int tid = threadIdx.x;
    for (int i = tid; i < nb; i += blockDim.x) buf[i] = bsum[i];
    __syncthreads();
    if (tid == 0) {
        int run = 0;
        for (int i = 0; i < nb; ++i) { int t = buf[i]; buf[i] = run; run += t; }
        *total = run;
    }
    __syncthreads();
    for (int i = tid; i < nb; i += blockDim.x) bsum[i] = buf[i];
}

__global__ __launch_bounds__(256) void scan_final_kernel(
    const int* __restrict__ deg, int n, const int* __restrict__ bsum,
    int* __restrict__ row_ptr, int* __restrict__ cursor) {
    int base = blockIdx.x * SCAN_CHUNK;
    int tid = threadIdx.x;
    int lane = tid & 63, wid = tid >> 6;
    int i = base + tid * 4;
    int4 v = make_int4(0, 0, 0, 0);
    if (i + 3 < n) v = *(const int4*)&deg[i];
    else {
        if (i + 0 < n) v.x = deg[i + 0];
        if (i + 1 < n) v.y = deg[i + 1];
        if (i + 2 < n) v.z = deg[i + 2];
        if (i + 3 < n) v.w = deg[i + 3];
    }
    int s = v.x + v.y + v.z + v.w;
    int inc = s;
    #pragma unroll
    for (int d = 1; d < 64; d <<= 1) {
        int t = __shfl_up(inc, d, 64);
        if (lane >= d) inc += t;
    }
    __shared__ int ws[4];
    if (lane == 63) ws[wid] = inc;
    __syncthreads();
    int woff = 0;
    for (int w = 0; w < wid; ++w) woff += ws[w];
    int ex = bsum[blockIdx.x] + woff + (inc - s);
    int e0 = ex, e1 = e0 + v.x, e2 = e1 + v.y, e3 = e2 + v.z;
    if (i + 3 < n) {
        *(int4*)&row_ptr[i] = make_int4(e0, e1, e2, e3);
        *(int4*)&cursor[i]  = make_int4(e0, e1, e2, e3);
    } else {
        if (i + 0 < n) { row_ptr[i + 0] = e0; cursor[i + 0] = e0; }
        if (i + 1 < n) { row_ptr[i + 1] = e1; cursor[i + 1] = e1; }
        if (i + 2 < n) { row_ptr[i + 2] = e2; cursor[i + 2] = e2; }
        if (i + 3 < n) { row_ptr[i + 3] = e3; cursor[i + 3] = e3; }
    }
}

__global__ void fill_csr_kernel(const int* __restrict__ ei, int E,
                                int* __restrict__ cursor, int* __restrict__ col) {
    int e = blockIdx.x * blockDim.x + threadIdx.x;
    if (e >= E) return;
    int src = ei[e];
    int dst = ei[(size_t)E + e];
    col[atomicAdd(&cursor[dst], 1)] = src;
}

// wcomb[k][o]: k<128 -> wl[o][k], k>=128 -> wr[o][k-128]   (256 x 128)
__global__ void build_wcomb_kernel(const float* __restrict__ wl,
                                   const float* __restrict__ wr,
                                   float* __restrict__ wcomb) {
    int idx = blockIdx.x * blockDim.x + threadIdx.x;
    if (idx >= 256 * 128) return;
    int k = idx >> 7, o = idx & 127;
    wcomb[idx] = (k < 128) ? wl[o * 128 + k] : wr[o * 128 + (k - 128)];
}

// ---------------- fp32 -> bf16 table ----------------

__global__ __launch_bounds__(256) void to_bf16_kernel(
    const float* __restrict__ in, u16* __restrict__ out, int n4) {
    int stride = gridDim.x * blockDim.x;
    for (int i = blockIdx.x * blockDim.x + threadIdx.x; i < n4; i += stride) {
        float4 v = *(const float4*)&in[(size_t)i * 4];
        ushort4 o;
        o.x = f2bf(v.x); o.y = f2bf(v.y); o.z = f2bf(v.z); o.w = f2bf(v.w);
        *(ushort4*)&out[(size_t)i * 4] = o;
    }
}

// ---------------- mean aggregation: bf16 gather, fp32 accumulate ----------------
// 16 lanes per node (8 dims each via one 16B load), 16 nodes per 256-block.
// Neighbor loop unrolled x4 -> 4 outstanding dwordx4 per thread.

__device__ inline void accum8(float acc[8], uint4 u) {
    const u32* p = (const u32*)&u;
    #pragma unroll
    for (int q = 0; q < 4; ++q) {
        u32 w = p[q];
        acc[2 * q]     += __uint_as_float(w << 16);
        acc[2 * q + 1] += __uint_as_float(w & 0xffff0000u);
    }
}

__global__ __launch_bounds__(256) void aggregate_bf16_kernel(
    const u16* __restrict__ feat, const int* __restrict__ row_ptr,
    const int* __restrict__ col, float* __restrict__ agg, int n) {
    int node = blockIdx.x * 16 + (threadIdx.x >> 4);
    if (node >= n) return;
    int l = threadIdx.x & 15;   // dims [8l, 8l+8)
    int beg = row_ptr[node], end = row_ptr[node + 1];
    float acc[8] = {0.f, 0.f, 0.f, 0.f, 0.f, 0.f, 0.f, 0.f};
    int j = beg;
    for (; j + 4 <= end; j += 4) {
        int s0 = col[j], s1 = col[j + 1], s2 = col[j + 2], s3 = col[j + 3];
        uint4 u0 = *(const uint4*)&feat[(size_t)s0 * NDIM + l * 8];
        uint4 u1 = *(const uint4*)&feat[(size_t)s1 * NDIM + l * 8];
        uint4 u2 = *(const uint4*)&feat[(size_t)s2 * NDIM + l * 8];
        uint4 u3 = *(const uint4*)&feat[(size_t)s3 * NDIM + l * 8];
        accum8(acc, u0); accum8(acc, u1); accum8(acc, u2); accum8(acc, u3);
    }
    for (; j < end; ++j) {
        uint4 u = *(const uint4*)&feat[(size_t)col[j] * NDIM + l * 8];
        accum8(acc, u);
    }
    float inv = (end > beg) ? 1.0f / (float)(end - beg) : 0.f;
    float4 o0 = make_float4(acc[0] * inv, acc[1] * inv, acc[2] * inv, acc[3] * inv);
    float4 o1 = make_float4(acc[4] * inv, acc[5] * inv, acc[6] * inv, acc[7] * inv);
    *(float4*)&agg[(size_t)node * NDIM + l * 8]     = o0;
    *(float4*)&agg[(size_t)node * NDIM + l * 8 + 4] = o1;
}

// fp32 fallback aggregate (if ws too small for bf16 tables)
__global__ __launch_bounds__(256) void aggregate_kernel(
    const float* __restrict__ feat, const int* __restrict__ row_ptr,
    const int* __restrict__ col, float* __restrict__ agg, int n) {
    int node = blockIdx.x * 2 + (threadIdx.x >> 7);
    if (node >= n) return;
    int t = threadIdx.x & 127;
    int beg = row_ptr[node], end = row_ptr[node + 1];
    float acc = 0.f;
    for (int j = beg; j < end; ++j) acc += feat[(size_t)col[j] * NDIM + t];
    float inv = (end > beg) ? 1.0f / (float)(end - beg) : 0.f;
    agg[(size_t)node * NDIM + t] = acc * inv;
}

// ---------------- fused GEMM: out = [A0|A1] @ Wc + bias (, relu) ----------------
// M x 256 @ 256 x 128. BM=64, BK=32, 256 threads, 4x8 acc per thread.
// Optionally also writes a bf16 copy of the output (h16) for the next gather.

__global__ __launch_bounds__(256) void gemm_fused_kernel(
    const float* __restrict__ A0, const float* __restrict__ A1,
    const float* __restrict__ Wc, const float* __restrict__ bias,
    float* __restrict__ out, u16* __restrict__ h16, int M, int do_relu) {
    __shared__ __align__(16) float As[64][36];
    __shared__ __align__(16) float Bs[32][128];
    const int tid = threadIdx.x;
    const int ty  = tid >> 4;
    const int tx  = tid & 15;
    const int m0  = blockIdx.x * 64;

    float acc[4][8];
    #pragma unroll
    for (int r = 0; r < 4; ++r)
        #pragma unroll
        for (int c = 0; c < 8; ++c) acc[r][c] = 0.f;

    for (int k0 = 0; k0 < 256; k0 += 32) {
        const float* Asrc = (k0 < 128) ? A0 : A1;
        const int kbase   = (k0 < 128) ? k0 : (k0 - 128);
        #pragma unroll
        for (int p = 0; p < 2; ++p) {
            int r  = (tid >> 3) + p * 32;
            int kk = (tid & 7) * 4;
            int gm = m0 + r;
            float4 v = make_float4(0.f, 0.f, 0.f, 0.f);
            if (gm < M) v = *(const float4*)&Asrc[(size_t)gm * NDIM + kbase + kk];
            *(float4*)&As[r][kk] = v;
        }
        #pragma unroll
        for (int p = 0; p < 4; ++p) {
            int r = (tid >> 5) + p * 8;
            int c = (tid & 31) * 4;
            *(float4*)&Bs[r][c] = *(const float4*)&Wc[(size_t)(k0 + r) * NDIM + c];
        }
        __syncthreads();
        #pragma unroll
        for (int kk = 0; kk < 32; ++kk) {
            float a[4];
            #pragma unroll
            for (int r = 0; r < 4; ++r) a[r] = As[ty * 4 + r][kk];
            float4 b0 = *(float4*)&Bs[kk][tx * 8];
            float4 b1 = *(float4*)&Bs[kk][tx * 8 + 4];
            float b[8] = {b0.x, b0.y, b0.z, b0.w, b1.x, b1.y, b1.z, b1.w};
            #pragma unroll
            for (int r = 0; r < 4; ++r)
                #pragma unroll
                for (int c = 0; c < 8; ++c)
                    acc[r][c] = fmaf(a[r], b[c], acc[r][c]);
        }
        __syncthreads();
    }

    #pragma unroll
    for (int r = 0; r < 4; ++r) {
        int gm = m0 + ty * 4 + r;
        if (gm >= M) continue;
        #pragma unroll
        for (int c = 0; c < 8; ++c) {
            float v = acc[r][c] + bias[tx * 8 + c];
            if (do_relu) v = fmaxf(v, 0.f);
            acc[r][c] = v;
        }
        *(float4*)&out[(size_t)gm * NDIM + tx * 8] =
            make_float4(acc[r][0], acc[r][1], acc[r][2], acc[r][3]);
        *(float4*)&out[(size_t)gm * NDIM + tx * 8 + 4] =
            make_float4(acc[r][4], acc[r][5], acc[r][6], acc[r][7]);
        if (h16) {
            ushort4 p0, p1;
            p0.x = f2bf(acc[r][0]); p0.y = f2bf(acc[r][1]);
            p0.z = f2bf(acc[r][2]); p0.w = f2bf(acc[r][3]);
            p1.x = f2bf(acc[r][4]); p1.y = f2bf(acc[r][5]);
            p1.z = f2bf(acc[r][6]); p1.w = f2bf(acc[r][7]);
            *(ushort4*)&h16[(size_t)gm * NDIM + tx * 8]     = p0;
            *(ushort4*)&h16[(size_t)gm * NDIM + tx * 8 + 4] = p1;
        }
    }
}

// ---------------- launch ----------------

extern "C" void kernel_launch(void* const* d_in, const int* in_sizes, int n_in,
                              void* d_out, int out_size, void* d_ws, size_t ws_size,
                              hipStream_t stream) {
    const float* x    = (const float*)d_in[0];
    const int*   ei   = (const int*)d_in[1];
    const float* w1_l = (const float*)d_in[2];
    const float* b1   = (const float*)d_in[3];
    const float* w1_r = (const float*)d_in[4];
    const float* w2_l = (const float*)d_in[5];
    const float* b2   = (const float*)d_in[6];
    const float* w2_r = (const float*)d_in[7];
    const int N = in_sizes[0] / NDIM;
    const int E = in_sizes[1] / 2;
    float* out = (float*)d_out;

    char* ws = (char*)d_ws;
    size_t off = 0;
    auto take = [&](size_t bytes) -> char* {
        char* p = ws + off;
        off += (bytes + 255) & ~(size_t)255;
        return p;
    };
    const int nb = (N + SCAN_CHUNK - 1) / SCAN_CHUNK;
    int*   deg     = (int*)take((size_t)N * 4);
    int*   row_ptr = (int*)take((size_t)(N + 1) * 4);
    int*   cursor  = (int*)take((size_t)N * 4);
    int*   bsum    = (int*)take((size_t)nb * 4);
    int*   col     = (int*)take((size_t)E * 4);
    float* wc1     = (float*)take(256 * 128 * 4);
    float* wc2     = (float*)take(256 * 128 * 4);
    float* agg     = (float*)take((size_t)N * NDIM * 4);
    size_t off_no16 = off;
    u16*   f16     = (u16*)take((size_t)N * NDIM * 2);  // x-bf16, then h-bf16 (sequential reuse)
    const bool use_bf16 = (off <= ws_size);

    hipMemsetAsync(deg, 0, (size_t)N * 4, stream);
    deg_count_kernel<<<(E + 255) / 256, 256, 0, stream>>>(ei, E, deg);
    scan_partial_kernel<<<nb, 256, 0, stream>>>(deg, N, bsum);
    scan_bsums_kernel<<<1, 256, 0, stream>>>(bsum, nb, row_ptr + N);
    scan_final_kernel<<<nb, 256, 0, stream>>>(deg, N, bsum, row_ptr, cursor);
    fill_csr_kernel<<<(E + 255) / 256, 256, 0, stream>>>(ei, E, cursor, col);
    build_wcomb_kernel<<<128, 256, 0, stream>>>(w1_l, w1_r, wc1);
    build_wcomb_kernel<<<128, 256, 0, stream>>>(w2_l, w2_r, wc2);

    if (use_bf16) {
        to_bf16_kernel<<<2048, 256, 0, stream>>>(x, f16, N * NDIM / 4);
        // layer 1
        aggregate_bf16_kernel<<<(N + 15) / 16, 256, 0, stream>>>(f16, row_ptr, col, agg, N);
        gemm_fused_kernel<<<(N + 63) / 64, 256, 0, stream>>>(agg, x, wc1, b1, out, f16, N, 1);
        // layer 2 (f16 now holds bf16(h))
        aggregate_bf16_kernel<<<(N + 15) / 16, 256, 0, stream>>>(f16, row_ptr, col, agg, N);
        gemm_fused_kernel<<<(N + 63) / 64, 256, 0, stream>>>(agg, out, wc2, b2, out, (u16*)0, N, 0);
    } else {
        (void)off_no16;
        aggregate_kernel<<<(N + 1) / 2, 256, 0, stream>>>(x, row_ptr, col, agg, N);
        gemm_fused_kernel<<<(N + 63) / 64, 256, 0, stream>>>(agg, x, wc1, b1, out, (u16*)0, N, 1);
        aggregate_kernel<<<(N + 1) / 2, 256, 0, stream>>>(out, row_ptr, col, agg, N);
        gemm_fused_kernel<<<(N + 63) / 64, 256, 0, stream>>>(agg, out, wc2, b2, out, (u16*)0, N, 0);
    }
}

// Round 4
// 547.619 us; speedup vs baseline: 1.8921x; 1.0008x over previous
//
#include <hip/hip_runtime.h>

#define NDIM 128
#define SCAN_CHUNK 1024

typedef unsigned short u16;
typedef unsigned int u32;

__device__ inline u16 f2bf(float f) {
    u32 u = __float_as_uint(f);
    u += 0x7fffu + ((u >> 16) & 1u);   // RNE
    return (u16)(u >> 16);
}

// ---------------- CSR build ----------------
// Harness delivers integer inputs as int32 (const int*).

__global__ void deg_count_kernel(const int* __restrict__ ei, int E,
                                 int* __restrict__ deg) {
    int e = blockIdx.x * blockDim.x + threadIdx.x;
    if (e >= E) return;
    atomicAdd(&deg[ei[(size_t)E + e]], 1);
}

// two-level scan: partial sums -> scan of partials -> final
__global__ __launch_bounds__(256) void scan_partial_kernel(
    const int* __restrict__ deg, int n, int* __restrict__ bsum) {
    int base = blockIdx.x * SCAN_CHUNK;
    int tid = threadIdx.x;
    int i = base + tid * 4;
    int4 v = make_int4(0, 0, 0, 0);
    if (i + 3 < n) v = *(const int4*)&deg[i];
    else {
        if (i + 0 < n) v.x = deg[i + 0];
        if (i + 1 < n) v.y = deg[i + 1];
        if (i + 2 < n) v.z = deg[i + 2];
        if (i + 3 < n) v.w = deg[i + 3];
    }
    int s = v.x + v.y + v.z + v.w;
    #pragma unroll
    for (int d = 1; d < 64; d <<= 1) s += __shfl_xor(s, d, 64);
    __shared__ int ws[4];
    if ((tid & 63) == 0) ws[tid >> 6] = s;
    __syncthreads();
    if (tid == 0) bsum[blockIdx.x] = ws[0] + ws[1] + ws[2] + ws[3];
}

__global__ void scan_bsums_kernel(int* __restrict__ bsum, int nb,
                                  int* __restrict__ total) {
    __shared__ int buf[512];
    int tid = threadIdx.x;
    for (int i = tid; i < nb; i += blockDim.x) buf[i] = bsum[i];
    __syncthreads();
    if (tid == 0) {
        int run = 0;
        for (int i = 0; i < nb; ++i) { int t = buf[i]; buf[i] = run; run += t; }
        *total = run;
    }
    __syncthreads();
    for (int i = tid; i < nb; i += blockDim.x) bsum[i] = buf[i];
}

__global__ __launch_bounds__(256) void scan_final_kernel(
    const int* __restrict__ deg, int n, const int* __restrict__ bsum,
    int* __restrict__ row_ptr, int* __restrict__ cursor) {
    int base = blockIdx.x * SCAN_CHUNK;
    int tid = threadIdx.x;
    int lane = tid & 63, wid = tid >> 6;
    int i = base + tid * 4;
    int4 v = make_int4(0, 0, 0, 0);
    if (i + 3 < n) v = *(const int4*)&deg[i];
    else {
        if (i + 0 < n) v.x = deg[i + 0];
        if (i + 1 < n) v.y = deg[i + 1];
        if (i + 2 < n) v.z = deg[i + 2];
        if (i + 3 < n) v.w = deg[i + 3];
    }
    int s = v.x + v.y + v.z + v.w;
    int inc = s;
    #pragma unroll
    for (int d = 1; d < 64; d <<= 1) {
        int t = __shfl_up(inc, d, 64);
        if (lane >= d) inc += t;
    }
    __shared__ int ws[4];
    if (lane == 63) ws[wid] = inc;
    __syncthreads();
    int woff = 0;
    for (int w = 0; w < wid; ++w) woff += ws[w];
    int ex = bsum[blockIdx.x] + woff + (inc - s);
    int e0 = ex, e1 = e0 + v.x, e2 = e1 + v.y, e3 = e2 + v.z;
    if (i + 3 < n) {
        *(int4*)&row_ptr[i] = make_int4(e0, e1, e2, e3);
        *(int4*)&cursor[i]  = make_int4(e0, e1, e2, e3);
    } else {
        if (i + 0 < n) { row_ptr[i + 0] = e0; cursor[i + 0] = e0; }
        if (i + 1 < n) { row_ptr[i + 1] = e1; cursor[i + 1] = e1; }
        if (i + 2 < n) { row_ptr[i + 2] = e2; cursor[i + 2] = e2; }
        if (i + 3 < n) { row_ptr[i + 3] = e3; cursor[i + 3] = e3; }
    }
}

__global__ void fill_csr_kernel(const int* __restrict__ ei, int E,
                                int* __restrict__ cursor, int* __restrict__ col) {
    int e = blockIdx.x * blockDim.x + threadIdx.x;
    if (e >= E) return;
    int src = ei[e];
    int dst = ei[(size_t)E + e];
    int slot = atomicAdd(&cursor[dst], 1);
    // NT store: scattered 4B writes; avoid L2 write-allocate + full-line writeback
    __builtin_nontemporal_store(src, &col[slot]);
}

// wcomb[k][o]: k<128 -> wl[o][k], k>=128 -> wr[o][k-128]   (256 x 128)
__global__ void build_wcomb_kernel(const float* __restrict__ wl,
                                   const float* __restrict__ wr,
                                   float* __restrict__ wcomb) {
    int idx = blockIdx.x * blockDim.x + threadIdx.x;
    if (idx >= 256 * 128) return;
    int k = idx >> 7, o = idx & 127;
    wcomb[idx] = (k < 128) ? wl[o * 128 + k] : wr[o * 128 + (k - 128)];
}

// ---------------- fp32 -> bf16 table ----------------

__global__ __launch_bounds__(256) void to_bf16_kernel(
    const float* __restrict__ in, u16* __restrict__ out, int n4) {
    int stride = gridDim.x * blockDim.x;
    for (int i = blockIdx.x * blockDim.x + threadIdx.x; i < n4; i += stride) {
        float4 v = *(const float4*)&in[(size_t)i * 4];
        ushort4 o;
        o.x = f2bf(v.x); o.y = f2bf(v.y); o.z = f2bf(v.z); o.w = f2bf(v.w);
        *(ushort4*)&out[(size_t)i * 4] = o;
    }
}

// ---------------- mean aggregation: bf16 gather, fp32 accumulate ----------------
// 16 lanes per node (8 dims each via one 16B load), 16 nodes per 256-block.
// Neighbor loop unrolled x4 -> 4 outstanding dwordx4 per thread.

__device__ inline void accum8(float acc[8], uint4 u) {
    const u32* p = (const u32*)&u;
    #pragma unroll
    for (int q = 0; q < 4; ++q) {
        u32 w = p[q];
        acc[2 * q]     += __uint_as_float(w << 16);
        acc[2 * q + 1] += __uint_as_float(w & 0xffff0000u);
    }
}

__global__ __launch_bounds__(256) void aggregate_bf16_kernel(
    const u16* __restrict__ feat, const int* __restrict__ row_ptr,
    const int* __restrict__ col, float* __restrict__ agg, int n) {
    int node = blockIdx.x * 16 + (threadIdx.x >> 4);
    if (node >= n) return;
    int l = threadIdx.x & 15;   // dims [8l, 8l+8)
    int beg = row_ptr[node], end = row_ptr[node + 1];
    float acc[8] = {0.f, 0.f, 0.f, 0.f, 0.f, 0.f, 0.f, 0.f};
    int j = beg;
    for (; j + 4 <= end; j += 4) {
        int s0 = col[j], s1 = col[j + 1], s2 = col[j + 2], s3 = col[j + 3];
        uint4 u0 = *(const uint4*)&feat[(size_t)s0 * NDIM + l * 8];
        uint4 u1 = *(const uint4*)&feat[(size_t)s1 * NDIM + l * 8];
        uint4 u2 = *(const uint4*)&feat[(size_t)s2 * NDIM + l * 8];
        uint4 u3 = *(const uint4*)&feat[(size_t)s3 * NDIM + l * 8];
        accum8(acc, u0); accum8(acc, u1); accum8(acc, u2); accum8(acc, u3);
    }
    for (; j < end; ++j) {
        uint4 u = *(const uint4*)&feat[(size_t)col[j] * NDIM + l * 8];
        accum8(acc, u);
    }
    float inv = (end > beg) ? 1.0f / (float)(end - beg) : 0.f;
    float4 o0 = make_float4(acc[0] * inv, acc[1] * inv, acc[2] * inv, acc[3] * inv);
    float4 o1 = make_float4(acc[4] * inv, acc[5] * inv, acc[6] * inv, acc[7] * inv);
    *(float4*)&agg[(size_t)node * NDIM + l * 8]     = o0;
    *(float4*)&agg[(size_t)node * NDIM + l * 8 + 4] = o1;
}

// fp32 fallback aggregate (only if ws too small for bf16 tables)
__global__ __launch_bounds__(256) void aggregate_kernel(
    const float* __restrict__ feat, const int* __restrict__ row_ptr,
    const int* __restrict__ col, float* __restrict__ agg, int n) {
    int node = blockIdx.x * 2 + (threadIdx.x >> 7);
    if (node >= n) return;
    int t = threadIdx.x & 127;
    int beg = row_ptr[node], end = row_ptr[node + 1];
    float acc = 0.f;
    for (int j = beg; j < end; ++j) acc += feat[(size_t)col[j] * NDIM + t];
    float inv = (end > beg) ? 1.0f / (float)(end - beg) : 0.f;
    agg[(size_t)node * NDIM + t] = acc * inv;
}

// ---------------- fused GEMM: out = [A0|A1] @ Wc + bias (, relu) ----------------
// M x 256 @ 256 x 128. BM=64, BK=32, 256 threads, 4x8 acc per thread.
// A staged transposed in LDS (As[kk][r]) so the per-kk A-frag is one ds_read_b128.
// Optionally also writes a bf16 copy of the output (h16) for the next gather.

__global__ __launch_bounds__(256) void gemm_fused_kernel(
    const float* __restrict__ A0, const float* __restrict__ A1,
    const float* __restrict__ Wc, const float* __restrict__ bias,
    float* __restrict__ out, u16* __restrict__ h16, int M, int do_relu) {
    __shared__ __align__(16) float As[32][68];   // [kk][r], stride 68 (16B-aligned rows)
    __shared__ __align__(16) float Bs[32][128];
    const int tid = threadIdx.x;
    const int ty  = tid >> 4;
    const int tx  = tid & 15;
    const int m0  = blockIdx.x * 64;

    float acc[4][8];
    #pragma unroll
    for (int r = 0; r < 4; ++r)
        #pragma unroll
        for (int c = 0; c < 8; ++c) acc[r][c] = 0.f;

    for (int k0 = 0; k0 < 256; k0 += 32) {
        const float* Asrc = (k0 < 128) ? A0 : A1;
        const int kbase   = (k0 < 128) ? k0 : (k0 - 128);
        #pragma unroll
        for (int p = 0; p < 2; ++p) {
            int r  = (tid >> 3) + p * 32;
            int kk = (tid & 7) * 4;
            int gm = m0 + r;
            float4 v = make_float4(0.f, 0.f, 0.f, 0.f);
            if (gm < M) v = *(const float4*)&Asrc[(size_t)gm * NDIM + kbase + kk];
            As[kk + 0][r] = v.x;
            As[kk + 1][r] = v.y;
            As[kk + 2][r] = v.z;
            As[kk + 3][r] = v.w;
        }
        #pragma unroll
        for (int p = 0; p < 4; ++p) {
            int r = (tid >> 5) + p * 8;
            int c = (tid & 31) * 4;
            *(float4*)&Bs[r][c] = *(const float4*)&Wc[(size_t)(k0 + r) * NDIM + c];
        }
        __syncthreads();
        #pragma unroll
        for (int kk = 0; kk < 32; ++kk) {
            float4 av = *(const float4*)&As[kk][ty * 4];
            float a[4] = {av.x, av.y, av.z, av.w};
            float4 b0 = *(float4*)&Bs[kk][tx * 8];
            float4 b1 = *(float4*)&Bs[kk][tx * 8 + 4];
            float b[8] = {b0.x, b0.y, b0.z, b0.w, b1.x, b1.y, b1.z, b1.w};
            #pragma unroll
            for (int r = 0; r < 4; ++r)
                #pragma unroll
                for (int c = 0; c < 8; ++c)
                    acc[r][c] = fmaf(a[r], b[c], acc[r][c]);
        }
        __syncthreads();
    }

    #pragma unroll
    for (int r = 0; r < 4; ++r) {
        int gm = m0 + ty * 4 + r;
        if (gm >= M) continue;
        #pragma unroll
        for (int c = 0; c < 8; ++c) {
            float v = acc[r][c] + bias[tx * 8 + c];
            if (do_relu) v = fmaxf(v, 0.f);
            acc[r][c] = v;
        }
        *(float4*)&out[(size_t)gm * NDIM + tx * 8] =
            make_float4(acc[r][0], acc[r][1], acc[r][2], acc[r][3]);
        *(float4*)&out[(size_t)gm * NDIM + tx * 8 + 4] =
            make_float4(acc[r][4], acc[r][5], acc[r][6], acc[r][7]);
        if (h16) {
            ushort4 p0, p1;
            p0.x = f2bf(acc[r][0]); p0.y = f2bf(acc[r][1]);
            p0.z = f2bf(acc[r][2]); p0.w = f2bf(acc[r][3]);
            p1.x = f2bf(acc[r][4]); p1.y = f2bf(acc[r][5]);
            p1.z = f2bf(acc[r][6]); p1.w = f2bf(acc[r][7]);
            *(ushort4*)&h16[(size_t)gm * NDIM + tx * 8]     = p0;
            *(ushort4*)&h16[(size_t)gm * NDIM + tx * 8 + 4] = p1;
        }
    }
}

// ---------------- launch ----------------

extern "C" void kernel_launch(void* const* d_in, const int* in_sizes, int n_in,
                              void* d_out, int out_size, void* d_ws, size_t ws_size,
                              hipStream_t stream) {
    const float* x    = (const float*)d_in[0];
    const int*   ei   = (const int*)d_in[1];
    const float* w1_l = (const float*)d_in[2];
    const float* b1   = (const float*)d_in[3];
    const float* w1_r = (const float*)d_in[4];
    const float* w2_l = (const float*)d_in[5];
    const float* b2   = (const float*)d_in[6];
    const float* w2_r = (const float*)d_in[7];
    const int N = in_sizes[0] / NDIM;
    const int E = in_sizes[1] / 2;
    float* out = (float*)d_out;

    char* ws = (char*)d_ws;
    size_t off = 0;
    auto take = [&](size_t bytes) -> char* {
        char* p = ws + off;
        off += (bytes + 255) & ~(size_t)255;
        return p;
    };
    const int nb = (N + SCAN_CHUNK - 1) / SCAN_CHUNK;
    int*   deg     = (int*)take((size_t)N * 4);
    int*   row_ptr = (int*)take((size_t)(N + 1) * 4);
    int*   cursor  = (int*)take((size_t)N * 4);
    int*   bsum    = (int*)take((size_t)nb * 4);
    int*   col     = (int*)take((size_t)E * 4);
    float* wc1     = (float*)take(256 * 128 * 4);
    float* wc2     = (float*)take(256 * 128 * 4);
    float* agg     = (float*)take((size_t)N * NDIM * 4);
    u16*   f16     = (u16*)take((size_t)N * NDIM * 2);  // x-bf16, then h-bf16 (sequential reuse)
    const bool use_bf16 = (off <= ws_size);

    hipMemsetAsync(deg, 0, (size_t)N * 4, stream);
    deg_count_kernel<<<(E + 255) / 256, 256, 0, stream>>>(ei, E, deg);
    scan_partial_kernel<<<nb, 256, 0, stream>>>(deg, N, bsum);
    scan_bsums_kernel<<<1, 256, 0, stream>>>(bsum, nb, row_ptr + N);
    scan_final_kernel<<<nb, 256, 0, stream>>>(deg, N, bsum, row_ptr, cursor);
    fill_csr_kernel<<<(E + 255) / 256, 256, 0, stream>>>(ei, E, cursor, col);
    build_wcomb_kernel<<<128, 256, 0, stream>>>(w1_l, w1_r, wc1);
    build_wcomb_kernel<<<128, 256, 0, stream>>>(w2_l, w2_r, wc2);

    if (use_bf16) {
        to_bf16_kernel<<<2048, 256, 0, stream>>>(x, f16, N * NDIM / 4);
        // layer 1
        aggregate_bf16_kernel<<<(N + 15) / 16, 256, 0, stream>>>(f16, row_ptr, col, agg, N);
        gemm_fused_kernel<<<(N + 63) / 64, 256, 0, stream>>>(agg, x, wc1, b1, out, f16, N, 1);
        // layer 2 (f16 now holds bf16(h))
        aggregate_bf16_kernel<<<(N + 15) / 16, 256, 0, stream>>>(f16, row_ptr, col, agg, N);
        gemm_fused_kernel<<<(N + 63) / 64, 256, 0, stream>>>(agg, out, wc2, b2, out, (u16*)0, N, 0);
    } else {
        aggregate_kernel<<<(N + 1) / 2, 256, 0, stream>>>(x, row_ptr, col, agg, N);
        gemm_fused_kernel<<<(N + 63) / 64, 256, 0, stream>>>(agg, x, wc1, b1, out, (u16*)0, N, 1);
        aggregate_kernel<<<(N + 1) / 2, 256, 0, stream>>>(out, row_ptr, col, agg, N);
        gemm_fused_kernel<<<(N + 63) / 64, 256, 0, stream>>>(agg, out, wc2, b2, out, (u16*)0, N, 0);
    }
}

// Round 5
// 390.919 us; speedup vs baseline: 2.6506x; 1.4009x over previous
//
#include <hip/hip_runtime.h>

#define NDIM 128
#define BKT_SHIFT 9            // 512 nodes per bucket
#define BKT_NODES 512
#define BKT_CAP   12288        // edges capacity per bucket (mean ~8163, +45 sigma)
#define PART_CHUNK 4096        // edges per block in partition kernel

typedef unsigned short u16;
typedef unsigned int u32;

__device__ inline u16 f2bf(float f) {
    u32 u = __float_as_uint(f);
    u += 0x7fffu + ((u >> 16) & 1u);   // RNE
    return (u16)(u >> 16);
}

// ---------------- bucketed CSR build ----------------
// Harness delivers integer inputs as int32 (const int*).
// Phase 1: partition edges into dst-range buckets (packed (src<<9)|dst_local).
// Phase 2: per-bucket CSR build fully in LDS; writes are bucket-local & dense.

__global__ __launch_bounds__(256) void partition_kernel(
    const int* __restrict__ ei, int E,
    int* __restrict__ gcur, u32* __restrict__ ebuf) {
    __shared__ int hcnt[256];
    __shared__ int hbase[256];
    const int tid = threadIdx.x;
    const int base = blockIdx.x * PART_CHUNK;
    hcnt[tid] = 0;
    __syncthreads();

    u32 val[16];
    int bkt[16];
    #pragma unroll
    for (int k = 0; k < 16; ++k) {
        int e = base + k * 256 + tid;
        bkt[k] = -1;
        if (e < E) {
            int src = ei[e];
            int dst = ei[(size_t)E + e];
            int b = dst >> BKT_SHIFT;
            bkt[k] = b;
            val[k] = ((u32)src << BKT_SHIFT) | (u32)(dst & (BKT_NODES - 1));
            atomicAdd(&hcnt[b], 1);
        }
    }
    __syncthreads();
    {
        int c = hcnt[tid];
        if (c > 0) hbase[tid] = atomicAdd(&gcur[tid], c);
        hcnt[tid] = 0;   // reuse as rank counter
    }
    __syncthreads();
    #pragma unroll
    for (int k = 0; k < 16; ++k) {
        if (bkt[k] >= 0) {
            int b = bkt[k];
            int r = atomicAdd(&hcnt[b], 1);
            int off = hbase[b] + r;
            if (off < BKT_CAP)
                ebuf[(size_t)b * BKT_CAP + off] = val[k];
        }
    }
}

__global__ __launch_bounds__(256) void bucket_csr_kernel(
    const int* __restrict__ gcur, const u32* __restrict__ ebuf,
    int* __restrict__ row_beg, int* __restrict__ degN,
    int* __restrict__ col, int n) {
    __shared__ int deg_l[BKT_NODES];
    __shared__ int pre_l[BKT_NODES];
    __shared__ int cur_l[BKT_NODES];
    __shared__ int wsum[4];
    const int tid = threadIdx.x;
    const int lane = tid & 63, wid = tid >> 6;
    const int b = blockIdx.x;
    const int node0 = b << BKT_SHIFT;
    int cnt = gcur[b];
    if (cnt > BKT_CAP) cnt = BKT_CAP;
    const size_t ebase = (size_t)b * BKT_CAP;

    deg_l[tid] = 0; deg_l[tid + 256] = 0;
    cur_l[tid] = 0; cur_l[tid + 256] = 0;
    __syncthreads();

    for (int i = tid; i < cnt; i += 256)
        atomicAdd(&deg_l[ebuf[ebase + i] & (BKT_NODES - 1)], 1);
    __syncthreads();

    // exclusive scan of deg_l[0..512): each thread owns 2 entries
    int v0 = deg_l[2 * tid], v1 = deg_l[2 * tid + 1];
    int s = v0 + v1, inc = s;
    #pragma unroll
    for (int d = 1; d < 64; d <<= 1) {
        int t = __shfl_up(inc, d, 64);
        if (lane >= d) inc += t;
    }
    if (lane == 63) wsum[wid] = inc;
    __syncthreads();
    int woff = 0;
    for (int w = 0; w < wid; ++w) woff += wsum[w];
    int ex = woff + (inc - s);
    pre_l[2 * tid] = ex;
    pre_l[2 * tid + 1] = ex + v0;
    __syncthreads();

    // write row_beg / deg for this bucket's nodes (coalesced)
    #pragma unroll
    for (int p = 0; p < 2; ++p) {
        int idx = tid + p * 256;
        int node = node0 + idx;
        if (node < n) {
            row_beg[node] = (int)ebase + pre_l[idx];
            degN[node]    = deg_l[idx];
        }
    }

    // scatter src into per-node contiguous slots (bucket-local region)
    for (int i = tid; i < cnt; i += 256) {
        u32 v = ebuf[ebase + i];
        int d = v & (BKT_NODES - 1);
        int r = atomicAdd(&cur_l[d], 1);
        col[ebase + pre_l[d] + r] = (int)(v >> BKT_SHIFT);
    }
}

// wcomb[k][o]: k<128 -> wl[o][k], k>=128 -> wr[o][k-128]   (256 x 128)
__global__ void build_wcomb_kernel(const float* __restrict__ wl,
                                   const float* __restrict__ wr,
                                   float* __restrict__ wcomb) {
    int idx = blockIdx.x * blockDim.x + threadIdx.x;
    if (idx >= 256 * 128) return;
    int k = idx >> 7, o = idx & 127;
    wcomb[idx] = (k < 128) ? wl[o * 128 + k] : wr[o * 128 + (k - 128)];
}

// ---------------- fp32 -> bf16 table ----------------

__global__ __launch_bounds__(256) void to_bf16_kernel(
    const float* __restrict__ in, u16* __restrict__ out, int n4) {
    int stride = gridDim.x * blockDim.x;
    for (int i = blockIdx.x * blockDim.x + threadIdx.x; i < n4; i += stride) {
        float4 v = *(const float4*)&in[(size_t)i * 4];
        ushort4 o;
        o.x = f2bf(v.x); o.y = f2bf(v.y); o.z = f2bf(v.z); o.w = f2bf(v.w);
        *(ushort4*)&out[(size_t)i * 4] = o;
    }
}

// ---------------- mean aggregation: bf16 gather, fp32 accumulate ----------------

__device__ inline void accum8(float acc[8], uint4 u) {
    const u32* p = (const u32*)&u;
    #pragma unroll
    for (int q = 0; q < 4; ++q) {
        u32 w = p[q];
        acc[2 * q]     += __uint_as_float(w << 16);
        acc[2 * q + 1] += __uint_as_float(w & 0xffff0000u);
    }
}

__global__ __launch_bounds__(256) void aggregate_bf16_kernel(
    const u16* __restrict__ feat, const int* __restrict__ row_beg,
    const int* __restrict__ degN, const int* __restrict__ col,
    float* __restrict__ agg, int n) {
    int node = blockIdx.x * 16 + (threadIdx.x >> 4);
    if (node >= n) return;
    int l = threadIdx.x & 15;   // dims [8l, 8l+8)
    int beg = row_beg[node];
    int dg  = degN[node];
    int end = beg + dg;
    float acc[8] = {0.f, 0.f, 0.f, 0.f, 0.f, 0.f, 0.f, 0.f};
    int j = beg;
    for (; j + 4 <= end; j += 4) {
        int s0 = col[j], s1 = col[j + 1], s2 = col[j + 2], s3 = col[j + 3];
        uint4 u0 = *(const uint4*)&feat[(size_t)s0 * NDIM + l * 8];
        uint4 u1 = *(const uint4*)&feat[(size_t)s1 * NDIM + l * 8];
        uint4 u2 = *(const uint4*)&feat[(size_t)s2 * NDIM + l * 8];
        uint4 u3 = *(const uint4*)&feat[(size_t)s3 * NDIM + l * 8];
        accum8(acc, u0); accum8(acc, u1); accum8(acc, u2); accum8(acc, u3);
    }
    for (; j < end; ++j) {
        uint4 u = *(const uint4*)&feat[(size_t)col[j] * NDIM + l * 8];
        accum8(acc, u);
    }
    float inv = (dg > 0) ? 1.0f / (float)dg : 0.f;
    float4 o0 = make_float4(acc[0] * inv, acc[1] * inv, acc[2] * inv, acc[3] * inv);
    float4 o1 = make_float4(acc[4] * inv, acc[5] * inv, acc[6] * inv, acc[7] * inv);
    *(float4*)&agg[(size_t)node * NDIM + l * 8]     = o0;
    *(float4*)&agg[(size_t)node * NDIM + l * 8 + 4] = o1;
}

// fp32 fallback aggregate (only if ws too small for bf16 tables)
__global__ __launch_bounds__(256) void aggregate_kernel(
    const float* __restrict__ feat, const int* __restrict__ row_beg,
    const int* __restrict__ degN, const int* __restrict__ col,
    float* __restrict__ agg, int n) {
    int node = blockIdx.x * 2 + (threadIdx.x >> 7);
    if (node >= n) return;
    int t = threadIdx.x & 127;
    int beg = row_beg[node];
    int dg  = degN[node];
    float acc = 0.f;
    for (int j = beg; j < beg + dg; ++j) acc += feat[(size_t)col[j] * NDIM + t];
    float inv = (dg > 0) ? 1.0f / (float)dg : 0.f;
    agg[(size_t)node * NDIM + t] = acc * inv;
}

// ---------------- fused GEMM: out = [A0|A1] @ Wc + bias (, relu) ----------------

__global__ __launch_bounds__(256) void gemm_fused_kernel(
    const float* __restrict__ A0, const float* __restrict__ A1,
    const float* __restrict__ Wc, const float* __restrict__ bias,
    float* __restrict__ out, u16* __restrict__ h16, int M, int do_relu) {
    __shared__ __align__(16) float As[32][68];   // [kk][r]
    __shared__ __align__(16) float Bs[32][128];
    const int tid = threadIdx.x;
    const int ty  = tid >> 4;
    const int tx  = tid & 15;
    const int m0  = blockIdx.x * 64;

    float acc[4][8];
    #pragma unroll
    for (int r = 0; r < 4; ++r)
        #pragma unroll
        for (int c = 0; c < 8; ++c) acc[r][c] = 0.f;

    for (int k0 = 0; k0 < 256; k0 += 32) {
        const float* Asrc = (k0 < 128) ? A0 : A1;
        const int kbase   = (k0 < 128) ? k0 : (k0 - 128);
        #pragma unroll
        for (int p = 0; p < 2; ++p) {
            int r  = (tid >> 3) + p * 32;
            int kk = (tid & 7) * 4;
            int gm = m0 + r;
            float4 v = make_float4(0.f, 0.f, 0.f, 0.f);
            if (gm < M) v = *(const float4*)&Asrc[(size_t)gm * NDIM + kbase + kk];
            As[kk + 0][r] = v.x;
            As[kk + 1][r] = v.y;
            As[kk + 2][r] = v.z;
            As[kk + 3][r] = v.w;
        }
        #pragma unroll
        for (int p = 0; p < 4; ++p) {
            int r = (tid >> 5) + p * 8;
            int c = (tid & 31) * 4;
            *(float4*)&Bs[r][c] = *(const float4*)&Wc[(size_t)(k0 + r) * NDIM + c];
        }
        __syncthreads();
        #pragma unroll
        for (int kk = 0; kk < 32; ++kk) {
            float4 av = *(const float4*)&As[kk][ty * 4];
            float a[4] = {av.x, av.y, av.z, av.w};
            float4 b0 = *(float4*)&Bs[kk][tx * 8];
            float4 b1 = *(float4*)&Bs[kk][tx * 8 + 4];
            float b[8] = {b0.x, b0.y, b0.z, b0.w, b1.x, b1.y, b1.z, b1.w};
            #pragma unroll
            for (int r = 0; r < 4; ++r)
                #pragma unroll
                for (int c = 0; c < 8; ++c)
                    acc[r][c] = fmaf(a[r], b[c], acc[r][c]);
        }
        __syncthreads();
    }

    #pragma unroll
    for (int r = 0; r < 4; ++r) {
        int gm = m0 + ty * 4 + r;
        if (gm >= M) continue;
        #pragma unroll
        for (int c = 0; c < 8; ++c) {
            float v = acc[r][c] + bias[tx * 8 + c];
            if (do_relu) v = fmaxf(v, 0.f);
            acc[r][c] = v;
        }
        *(float4*)&out[(size_t)gm * NDIM + tx * 8] =
            make_float4(acc[r][0], acc[r][1], acc[r][2], acc[r][3]);
        *(float4*)&out[(size_t)gm * NDIM + tx * 8 + 4] =
            make_float4(acc[r][4], acc[r][5], acc[r][6], acc[r][7]);
        if (h16) {
            ushort4 p0, p1;
            p0.x = f2bf(acc[r][0]); p0.y = f2bf(acc[r][1]);
            p0.z = f2bf(acc[r][2]); p0.w = f2bf(acc[r][3]);
            p1.x = f2bf(acc[r][4]); p1.y = f2bf(acc[r][5]);
            p1.z = f2bf(acc[r][6]); p1.w = f2bf(acc[r][7]);
            *(ushort4*)&h16[(size_t)gm * NDIM + tx * 8]     = p0;
            *(ushort4*)&h16[(size_t)gm * NDIM + tx * 8 + 4] = p1;
        }
    }
}

// ---------------- launch ----------------

extern "C" void kernel_launch(void* const* d_in, const int* in_sizes, int n_in,
                              void* d_out, int out_size, void* d_ws, size_t ws_size,
                              hipStream_t stream) {
    const float* x    = (const float*)d_in[0];
    const int*   ei   = (const int*)d_in[1];
    const float* w1_l = (const float*)d_in[2];
    const float* b1   = (const float*)d_in[3];
    const float* w1_r = (const float*)d_in[4];
    const float* w2_l = (const float*)d_in[5];
    const float* b2   = (const float*)d_in[6];
    const float* w2_r = (const float*)d_in[7];
    const int N = in_sizes[0] / NDIM;
    const int E = in_sizes[1] / 2;
    float* out = (float*)d_out;

    const int NB = (N + BKT_NODES - 1) >> BKT_SHIFT;   // 196 for N=100K (<=256 assumed)

    char* ws = (char*)d_ws;
    size_t off = 0;
    auto take = [&](size_t bytes) -> char* {
        char* p = ws + off;
        off += (bytes + 255) & ~(size_t)255;
        return p;
    };
    int*   row_beg = (int*)take((size_t)N * 4);
    int*   degN    = (int*)take((size_t)N * 4);
    int*   gcur    = (int*)take((size_t)NB * 4);
    u32*   ebuf    = (u32*)take((size_t)NB * BKT_CAP * 4);
    int*   col     = (int*)take((size_t)NB * BKT_CAP * 4);
    float* wc1     = (float*)take(256 * 128 * 4);
    float* wc2     = (float*)take(256 * 128 * 4);
    float* agg     = (float*)take((size_t)N * NDIM * 4);
    u16*   f16     = (u16*)take((size_t)N * NDIM * 2);  // x-bf16, then h-bf16
    const bool use_bf16 = (off <= ws_size);

    hipMemsetAsync(gcur, 0, (size_t)NB * 4, stream);
    partition_kernel<<<(E + PART_CHUNK - 1) / PART_CHUNK, 256, 0, stream>>>(ei, E, gcur, ebuf);
    bucket_csr_kernel<<<NB, 256, 0, stream>>>(gcur, ebuf, row_beg, degN, col, N);
    build_wcomb_kernel<<<128, 256, 0, stream>>>(w1_l, w1_r, wc1);
    build_wcomb_kernel<<<128, 256, 0, stream>>>(w2_l, w2_r, wc2);

    if (use_bf16) {
        to_bf16_kernel<<<2048, 256, 0, stream>>>(x, f16, N * NDIM / 4);
        // layer 1
        aggregate_bf16_kernel<<<(N + 15) / 16, 256, 0, stream>>>(f16, row_beg, degN, col, agg, N);
        gemm_fused_kernel<<<(N + 63) / 64, 256, 0, stream>>>(agg, x, wc1, b1, out, f16, N, 1);
        // layer 2 (f16 now holds bf16(h))
        aggregate_bf16_kernel<<<(N + 15) / 16, 256, 0, stream>>>(f16, row_beg, degN, col, agg, N);
        gemm_fused_kernel<<<(N + 63) / 64, 256, 0, stream>>>(agg, out, wc2, b2, out, (u16*)0, N, 0);
    } else {
        aggregate_kernel<<<(N + 1) / 2, 256, 0, stream>>>(x, row_beg, degN, col, agg, N);
        gemm_fused_kernel<<<(N + 63) / 64, 256, 0, stream>>>(agg, x, wc1, b1, out, (u16*)0, N, 1);
        aggregate_kernel<<<(N + 1) / 2, 256, 0, stream>>>(out, row_beg, degN, col, agg, N);
        gemm_fused_kernel<<<(N + 63) / 64, 256, 0, stream>>>(agg, out, wc2, b2, out, (u16*)0, N, 0);
    }
}

// Round 6
// 326.779 us; speedup vs baseline: 3.1708x; 1.1963x over previous
//
#include <hip/hip_runtime.h>

#define NDIM 128
#define BKT_SHIFT 9            // 512 nodes per bucket
#define BKT_NODES 512
#define BKT_CAP   12288        // edges capacity per bucket (mean ~8163)
#define PART_CHUNK 4096        // edges per block in partition kernel

typedef unsigned short u16;
typedef unsigned int u32;
typedef __attribute__((ext_vector_type(8))) short bf16x8;
typedef __attribute__((ext_vector_type(4))) float f32x4;

__device__ inline u16 f2bf(float f) {
    u32 u = __float_as_uint(f);
    u += 0x7fffu + ((u >> 16) & 1u);   // RNE
    return (u16)(u >> 16);
}
__device__ inline float bf2f(u16 h) { return __uint_as_float((u32)h << 16); }

// ---------------- bucketed CSR build (unchanged from R5 — it worked) ----------------

__global__ __launch_bounds__(256) void partition_kernel(
    const int* __restrict__ ei, int E,
    int* __restrict__ gcur, u32* __restrict__ ebuf) {
    __shared__ int hcnt[256];
    __shared__ int hbase[256];
    const int tid = threadIdx.x;
    const int base = blockIdx.x * PART_CHUNK;
    hcnt[tid] = 0;
    __syncthreads();

    u32 val[16];
    int bkt[16];
    #pragma unroll
    for (int k = 0; k < 16; ++k) {
        int e = base + k * 256 + tid;
        bkt[k] = -1;
        if (e < E) {
            int src = ei[e];
            int dst = ei[(size_t)E + e];
            int b = dst >> BKT_SHIFT;
            bkt[k] = b;
            val[k] = ((u32)src << BKT_SHIFT) | (u32)(dst & (BKT_NODES - 1));
            atomicAdd(&hcnt[b], 1);
        }
    }
    __syncthreads();
    {
        int c = hcnt[tid];
        if (c > 0) hbase[tid] = atomicAdd(&gcur[tid], c);
        hcnt[tid] = 0;   // reuse as rank counter
    }
    __syncthreads();
    #pragma unroll
    for (int k = 0; k < 16; ++k) {
        if (bkt[k] >= 0) {
            int b = bkt[k];
            int r = atomicAdd(&hcnt[b], 1);
            int off = hbase[b] + r;
            if (off < BKT_CAP)
                ebuf[(size_t)b * BKT_CAP + off] = val[k];
        }
    }
}

__global__ __launch_bounds__(256) void bucket_csr_kernel(
    const int* __restrict__ gcur, const u32* __restrict__ ebuf,
    int* __restrict__ row_beg, int* __restrict__ degN,
    int* __restrict__ col, int n) {
    __shared__ int deg_l[BKT_NODES];
    __shared__ int pre_l[BKT_NODES];
    __shared__ int cur_l[BKT_NODES];
    __shared__ int wsum[4];
    const int tid = threadIdx.x;
    const int lane = tid & 63, wid = tid >> 6;
    const int b = blockIdx.x;
    const int node0 = b << BKT_SHIFT;
    int cnt = gcur[b];
    if (cnt > BKT_CAP) cnt = BKT_CAP;
    const size_t ebase = (size_t)b * BKT_CAP;

    deg_l[tid] = 0; deg_l[tid + 256] = 0;
    cur_l[tid] = 0; cur_l[tid + 256] = 0;
    __syncthreads();

    for (int i = tid; i < cnt; i += 256)
        atomicAdd(&deg_l[ebuf[ebase + i] & (BKT_NODES - 1)], 1);
    __syncthreads();

    int v0 = deg_l[2 * tid], v1 = deg_l[2 * tid + 1];
    int s = v0 + v1, inc = s;
    #pragma unroll
    for (int d = 1; d < 64; d <<= 1) {
        int t = __shfl_up(inc, d, 64);
        if (lane >= d) inc += t;
    }
    if (lane == 63) wsum[wid] = inc;
    __syncthreads();
    int woff = 0;
    for (int w = 0; w < wid; ++w) woff += wsum[w];
    int ex = woff + (inc - s);
    pre_l[2 * tid] = ex;
    pre_l[2 * tid + 1] = ex + v0;
    __syncthreads();

    #pragma unroll
    for (int p = 0; p < 2; ++p) {
        int idx = tid + p * 256;
        int node = node0 + idx;
        if (node < n) {
            row_beg[node] = (int)ebase + pre_l[idx];
            degN[node]    = deg_l[idx];
        }
    }

    for (int i = tid; i < cnt; i += 256) {
        u32 v = ebuf[ebase + i];
        int d = v & (BKT_NODES - 1);
        int r = atomicAdd(&cur_l[d], 1);
        col[ebase + pre_l[d] + r] = (int)(v >> BKT_SHIFT);
    }
}

// ---------------- weight prep: Wt[o][k] split bf16 hi/lo, k = [w_l | w_r] ----------------

__global__ void build_wt_kernel(const float* __restrict__ wl,
                                const float* __restrict__ wr,
                                u16* __restrict__ wth, u16* __restrict__ wtl) {
    int idx = blockIdx.x * blockDim.x + threadIdx.x;
    if (idx >= 128 * 256) return;
    int o = idx >> 8, k = idx & 255;
    float v = (k < 128) ? wl[o * 128 + k] : wr[o * 128 + (k - 128)];
    u16 hi = f2bf(v);
    wth[idx] = hi;
    wtl[idx] = f2bf(v - bf2f(hi));
}

// ---------------- fp32 -> bf16(hi) table ----------------

__global__ __launch_bounds__(256) void to_bf16_kernel(
    const float* __restrict__ in, u16* __restrict__ out, int n4) {
    int stride = gridDim.x * blockDim.x;
    for (int i = blockIdx.x * blockDim.x + threadIdx.x; i < n4; i += stride) {
        float4 v = *(const float4*)&in[(size_t)i * 4];
        ushort4 o;
        o.x = f2bf(v.x); o.y = f2bf(v.y); o.z = f2bf(v.z); o.w = f2bf(v.w);
        *(ushort4*)&out[(size_t)i * 4] = o;
    }
}

// ---------------- mean aggregation: bf16 gather, fp32 accum, split hi/lo out ----------------

__device__ inline void accum8(float acc[8], uint4 u) {
    const u32* p = (const u32*)&u;
    #pragma unroll
    for (int q = 0; q < 4; ++q) {
        u32 w = p[q];
        acc[2 * q]     += __uint_as_float(w << 16);
        acc[2 * q + 1] += __uint_as_float(w & 0xffff0000u);
    }
}

__global__ __launch_bounds__(256) void aggregate_bf16_kernel(
    const u16* __restrict__ feat, const int* __restrict__ row_beg,
    const int* __restrict__ degN, const int* __restrict__ col,
    u16* __restrict__ aggh, u16* __restrict__ aggl, int n) {
    int node = blockIdx.x * 16 + (threadIdx.x >> 4);
    if (node >= n) return;
    int l = threadIdx.x & 15;   // dims [8l, 8l+8)
    int beg = row_beg[node];
    int dg  = degN[node];
    int end = beg + dg;
    float acc[8] = {0.f, 0.f, 0.f, 0.f, 0.f, 0.f, 0.f, 0.f};
    int j = beg;
    for (; j + 4 <= end; j += 4) {
        int s0 = col[j], s1 = col[j + 1], s2 = col[j + 2], s3 = col[j + 3];
        uint4 u0 = *(const uint4*)&feat[(size_t)s0 * NDIM + l * 8];
        uint4 u1 = *(const uint4*)&feat[(size_t)s1 * NDIM + l * 8];
        uint4 u2 = *(const uint4*)&feat[(size_t)s2 * NDIM + l * 8];
        uint4 u3 = *(const uint4*)&feat[(size_t)s3 * NDIM + l * 8];
        accum8(acc, u0); accum8(acc, u1); accum8(acc, u2); accum8(acc, u3);
    }
    for (; j < end; ++j) {
        uint4 u = *(const uint4*)&feat[(size_t)col[j] * NDIM + l * 8];
        accum8(acc, u);
    }
    float inv = (dg > 0) ? 1.0f / (float)dg : 0.f;
    ushort4 h0, h1, l0, l1;
    u16 hs[8], ls[8];
    #pragma unroll
    for (int q = 0; q < 8; ++q) {
        float v = acc[q] * inv;
        u16 hi = f2bf(v);
        hs[q] = hi;
        ls[q] = f2bf(v - bf2f(hi));
    }
    h0 = make_ushort4(hs[0], hs[1], hs[2], hs[3]);
    h1 = make_ushort4(hs[4], hs[5], hs[6], hs[7]);
    l0 = make_ushort4(ls[0], ls[1], ls[2], ls[3]);
    l1 = make_ushort4(ls[4], ls[5], ls[6], ls[7]);
    *(ushort4*)&aggh[(size_t)node * NDIM + l * 8]     = h0;
    *(ushort4*)&aggh[(size_t)node * NDIM + l * 8 + 4] = h1;
    *(ushort4*)&aggl[(size_t)node * NDIM + l * 8]     = l0;
    *(ushort4*)&aggl[(size_t)node * NDIM + l * 8 + 4] = l1;
}

// ---------------- MFMA GEMM: out = [agg | xh] @ Wt^T + bias ----------------
// A: K<128 from (aggh + aggl) split; K>=128 from xh (single bf16).
// B: Wt[o][k] split hi/lo. D fp32 in AGPR-file.
// Block = 128 rows x 128 cols, 4 waves in 2x2. No LDS: fragments direct from global.
// mfma_f32_16x16x32_bf16 layout: A row=lane&15, k=(lane>>4)*8+j;
// B col=lane&15 (Wt row), same k; D col=lane&15, row=(lane>>4)*4+reg.

__global__ __launch_bounds__(256) void gemm_mfma_kernel(
    const u16* __restrict__ aggh, const u16* __restrict__ aggl,
    const u16* __restrict__ xh,
    const u16* __restrict__ wth, const u16* __restrict__ wtl,
    const float* __restrict__ bias,
    float* __restrict__ outF, u16* __restrict__ outH,
    int M, int do_relu) {
    const int tid  = threadIdx.x;
    const int lane = tid & 63;
    const int wid  = tid >> 6;
    const int wr = wid >> 1, wc = wid & 1;     // 2x2 wave grid: 64x64 each
    const int rr = lane & 15, kb = lane >> 4;  // rr: row/col-in-tile, kb: k-block
    const int m0 = blockIdx.x * 128;

    // A-load rows (clamped for the tail block)
    int arow[4];
    #pragma unroll
    for (int mt = 0; mt < 4; ++mt) {
        int r = m0 + wr * 64 + mt * 16 + rr;
        arow[mt] = (r < M) ? r : (M - 1);
    }
    // B rows (Wt row = output col)
    const u16* wthp[4]; const u16* wtlp[4];
    #pragma unroll
    for (int nt = 0; nt < 4; ++nt) {
        int c = wc * 64 + nt * 16 + rr;
        wthp[nt] = &wth[(size_t)c * 256];
        wtlp[nt] = &wtl[(size_t)c * 256];
    }

    f32x4 acc[4][4];
    #pragma unroll
    for (int mt = 0; mt < 4; ++mt)
        #pragma unroll
        for (int nt = 0; nt < 4; ++nt)
            acc[mt][nt] = (f32x4){0.f, 0.f, 0.f, 0.f};

    #pragma unroll
    for (int ks = 0; ks < 8; ++ks) {
        const int kfrag = ks * 32 + kb * 8;      // k offset of this lane's 8 elems
        bf16x8 bh[4], bl[4];
        #pragma unroll
        for (int nt = 0; nt < 4; ++nt) {
            bh[nt] = *(const bf16x8*)&wthp[nt][kfrag];
            bl[nt] = *(const bf16x8*)&wtlp[nt][kfrag];
        }
        if (ks < 4) {
            const int ka = ks * 32 + kb * 8;
            bf16x8 ah[4], al[4];
            #pragma unroll
            for (int mt = 0; mt < 4; ++mt) {
                ah[mt] = *(const bf16x8*)&aggh[(size_t)arow[mt] * NDIM + ka];
                al[mt] = *(const bf16x8*)&aggl[(size_t)arow[mt] * NDIM + ka];
            }
            #pragma unroll
            for (int mt = 0; mt < 4; ++mt)
                #pragma unroll
                for (int nt = 0; nt < 4; ++nt) {
                    acc[mt][nt] = __builtin_amdgcn_mfma_f32_16x16x32_bf16(ah[mt], bh[nt], acc[mt][nt], 0, 0, 0);
                    acc[mt][nt] = __builtin_amdgcn_mfma_f32_16x16x32_bf16(al[mt], bh[nt], acc[mt][nt], 0, 0, 0);
                    acc[mt][nt] = __builtin_amdgcn_mfma_f32_16x16x32_bf16(ah[mt], bl[nt], acc[mt][nt], 0, 0, 0);
                }
        } else {
            const int ka = (ks - 4) * 32 + kb * 8;
            bf16x8 ah[4];
            #pragma unroll
            for (int mt = 0; mt < 4; ++mt)
                ah[mt] = *(const bf16x8*)&xh[(size_t)arow[mt] * NDIM + ka];
            #pragma unroll
            for (int mt = 0; mt < 4; ++mt)
                #pragma unroll
                for (int nt = 0; nt < 4; ++nt) {
                    acc[mt][nt] = __builtin_amdgcn_mfma_f32_16x16x32_bf16(ah[mt], bh[nt], acc[mt][nt], 0, 0, 0);
                    acc[mt][nt] = __builtin_amdgcn_mfma_f32_16x16x32_bf16(ah[mt], bl[nt], acc[mt][nt], 0, 0, 0);
                }
        }
    }

    // epilogue: D col = lane&15 (=rr), row = kb*4 + reg
    #pragma unroll
    for (int nt = 0; nt < 4; ++nt) {
        int gcol = wc * 64 + nt * 16 + rr;
        float bb = bias[gcol];
        #pragma unroll
        for (int mt = 0; mt < 4; ++mt) {
            #pragma unroll
            for (int r = 0; r < 4; ++r) {
                int grow = m0 + wr * 64 + mt * 16 + kb * 4 + r;
                if (grow < M) {
                    float v = acc[mt][nt][r] + bb;
                    if (do_relu) v = fmaxf(v, 0.f);
                    if (outF) outF[(size_t)grow * NDIM + gcol] = v;
                    if (outH) outH[(size_t)grow * NDIM + gcol] = f2bf(v);
                }
            }
        }
    }
}

// ---------------- launch ----------------

extern "C" void kernel_launch(void* const* d_in, const int* in_sizes, int n_in,
                              void* d_out, int out_size, void* d_ws, size_t ws_size,
                              hipStream_t stream) {
    const float* x    = (const float*)d_in[0];
    const int*   ei   = (const int*)d_in[1];
    const float* w1_l = (const float*)d_in[2];
    const float* b1   = (const float*)d_in[3];
    const float* w1_r = (const float*)d_in[4];
    const float* w2_l = (const float*)d_in[5];
    const float* b2   = (const float*)d_in[6];
    const float* w2_r = (const float*)d_in[7];
    const int N = in_sizes[0] / NDIM;
    const int E = in_sizes[1] / 2;
    float* out = (float*)d_out;

    const int NB = (N + BKT_NODES - 1) >> BKT_SHIFT;

    char* ws = (char*)d_ws;
    size_t off = 0;
    auto take = [&](size_t bytes) -> char* {
        char* p = ws + off;
        off += (bytes + 255) & ~(size_t)255;
        return p;
    };
    int* row_beg = (int*)take((size_t)N * 4);
    int* degN    = (int*)take((size_t)N * 4);
    int* gcur    = (int*)take((size_t)NB * 4);
    u32* ebuf    = (u32*)take((size_t)NB * BKT_CAP * 4);
    int* colA    = (int*)take((size_t)NB * BKT_CAP * 4);
    u16* wt1h    = (u16*)take(128 * 256 * 2);
    u16* wt1l    = (u16*)take(128 * 256 * 2);
    u16* wt2h    = (u16*)take(128 * 256 * 2);
    u16* wt2l    = (u16*)take(128 * 256 * 2);
    u16* aggh    = (u16*)take((size_t)N * NDIM * 2);
    u16* aggl    = (u16*)take((size_t)N * NDIM * 2);
    u16* hh      = (u16*)take((size_t)N * NDIM * 2);
    // xh lives in d_out: free scratch until the layer-2 epilogue overwrites it
    u16* xh      = (u16*)d_out;

    hipMemsetAsync(gcur, 0, (size_t)NB * 4, stream);
    partition_kernel<<<(E + PART_CHUNK - 1) / PART_CHUNK, 256, 0, stream>>>(ei, E, gcur, ebuf);
    bucket_csr_kernel<<<NB, 256, 0, stream>>>(gcur, ebuf, row_beg, degN, colA, N);
    build_wt_kernel<<<128, 256, 0, stream>>>(w1_l, w1_r, wt1h, wt1l);
    build_wt_kernel<<<128, 256, 0, stream>>>(w2_l, w2_r, wt2h, wt2l);
    to_bf16_kernel<<<2048, 256, 0, stream>>>(x, xh, N * NDIM / 4);

    const int gblk = (N + 127) / 128;
    // layer 1: h_hi = bf16(relu([mean(x) | x] @ Wt1 + b1))   (no fp32 h)
    aggregate_bf16_kernel<<<(N + 15) / 16, 256, 0, stream>>>(xh, row_beg, degN, colA, aggh, aggl, N);
    gemm_mfma_kernel<<<gblk, 256, 0, stream>>>(aggh, aggl, xh, wt1h, wt1l, b1,
                                               (float*)0, hh, N, 1);
    // layer 2: out = [mean(h) | h] @ Wt2 + b2  (fp32, overwrites xh scratch in d_out)
    aggregate_bf16_kernel<<<(N + 15) / 16, 256, 0, stream>>>(hh, row_beg, degN, colA, aggh, aggl, N);
    gemm_mfma_kernel<<<gblk, 256, 0, stream>>>(aggh, aggl, hh, wt2h, wt2l, b2,
                                               out, (u16*)0, N, 0);
}